// Round 13
// baseline (173.310 us; speedup 1.0000x reference)
//
#include <hip/hip_runtime.h>
#include <cstdint>

// Dynamic_MLP_C: fused bf16-MFMA implementation.
//
// Reformulation: x[t,o] = sum_k A[t,k] * B[k,o],  k = j*64+i  (K = 4160)
//   A[t, j*64+i] = w21[t,j] * w12[t,i]  (rank-1), bias rows A[t,4096+i]=w12[t,i].
// Re-association: x[t,o] = sum_j w21[t,j] * (w12[t,:] @ B_j)[o]
//   -> A-fragment = CONSTANT w12 regs; per j: 2 MFMAs -> m; acc += w21[t,j]*m.
//
// R7-R12 history: barrier-free K-loop reading B (532 KB, L2-resident) straight
// into named VGPR buffers. R9 (mf=4, 64-tok blocks): 272 MB traffic but only
// 2-3 waves/SIMD -> latency-exposed. R12 (mf=2, 32-tok blocks): 4 waves/SIMD
// but 545 MB traffic -> BW-exposed. Both ~32 us. R13 = both at once:
// mf=4 (proven 128-VGPR, no spill) + LDS overlays -> 35.3 KB/block ->
// 4 blocks/CU: 272 MB traffic AND 4 waves/SIMD.

typedef __bf16 bf16x4 __attribute__((ext_vector_type(4)));
typedef __bf16 bf16x8 __attribute__((ext_vector_type(8)));
typedef float  f32x4  __attribute__((ext_vector_type(4)));

#define MFMA16(A, B, C) __builtin_amdgcn_mfma_f32_16x16x32_bf16(A, B, C, 0, 0, 0)

// workspace element offsets (bf16 elements)
#define OFF_BT22 0         // K=4160 grouped layout, 266240 elems
#define OFF_W11  266240    // K=128,  8192 (frag layout)
#define OFF_W21  274432    // K=128,  8192
#define OFF_W12  282624    // K=64,   4096
#define OFF_W3   286720    // K=64,   4096

// prep: [64 k x 64 o] fp32 tile -> bf16.
//  W22/b22 tiles: grouped layout ws[((o>>4)*520 + k8)*128 + (o&15)*8 + (k&7)]
//  small weights: frag layout    ws[base + (k>>3)*512 + o*8 + (k&7)]
__global__ __launch_bounds__(256) void prep_kernel(
    const float* __restrict__ W22, const float* __restrict__ b22,
    const float* __restrict__ W11, const float* __restrict__ W21,
    const float* __restrict__ W12, const float* __restrict__ W3,
    __bf16* __restrict__ ws)
{
    __shared__ __bf16 T[64][72];
    const int b = blockIdx.x, tid = threadIdx.x;
    const float* src; long base = 0;
    if (b < 64)       { src = W22 + b * 4096; }
    else if (b == 64) { src = b22; }
    else if (b < 67)  { src = W11 + (b - 65) * 4096; base = OFF_W11 + (b - 65) * 4096; }
    else if (b < 69)  { src = W21 + (b - 67) * 4096; base = OFF_W21 + (b - 67) * 4096; }
    else if (b == 69) { src = W12;                   base = OFF_W12; }
    else              { src = W3;                    base = OFF_W3; }
    #pragma unroll
    for (int it = 0; it < 4; ++it) {
        int u = it * 1024 + tid * 4;
        int r = u >> 6, c = u & 63;
        const float4 v = *(const float4*)(src + u);
        T[r][c] = (__bf16)v.x; T[r][c + 1] = (__bf16)v.y;
        T[r][c + 2] = (__bf16)v.z; T[r][c + 3] = (__bf16)v.w;
    }
    __syncthreads();
    #pragma unroll
    for (int it = 0; it < 2; ++it) {
        int item = it * 256 + tid;
        int q = item >> 6, o = item & 63;
        bf16x8 pk;
        #pragma unroll
        for (int kj = 0; kj < 8; ++kj) pk[kj] = T[q * 8 + kj][o];
        long dstE;
        if (b <= 64) {
            int k8 = (b == 64 ? 512 : b * 8) + q;
            dstE = OFF_BT22 + ((long)(o >> 4) * 520 + k8) * 128 + (o & 15) * 8;
        } else {
            dstE = base + q * 512 + o * 8;
        }
        *(bf16x8*)(ws + dstE) = pk;
    }
}

// ---- register chunk-buffer machinery: named registers, token-pasted ----
#define LOADCH(buf, c) do {                                          \
    buf##_0 = *(const bf16x8*)(Bw + ((c)*16 +  0) * 128);            \
    buf##_1 = *(const bf16x8*)(Bw + ((c)*16 +  4) * 128);            \
    buf##_2 = *(const bf16x8*)(Bw + ((c)*16 +  8) * 128);            \
    buf##_3 = *(const bf16x8*)(Bw + ((c)*16 + 12) * 128);            \
} while (0)

#define COMPUTE_J(b0, b1, j) do {                                    \
    f32x4 w4[4];                                                     \
    _Pragma("unroll")                                                \
    for (int mf = 0; mf < 4; ++mf) {                                 \
        bf16x4 wv4 = *(const bf16x4*)(w21T + (j)*68 + mf*16 + quad*4);\
        w4[mf] = __builtin_convertvector(wv4, f32x4);                \
    }                                                                \
    _Pragma("unroll")                                                \
    for (int mf = 0; mf < 4; ++mf) {                                 \
        f32x4 fz = {};                                               \
        f32x4 m = MFMA16(a12[mf][0], b0, fz);                        \
        m       = MFMA16(a12[mf][1], b1, m);                         \
        _Pragma("unroll")                                            \
        for (int r = 0; r < 4; ++r)                                  \
            acc[mf][r] = fmaf(w4[mf][r], m[r], acc[mf][r]);          \
    }                                                                \
} while (0)

#define COMPUTE(buf, c) do {                                         \
    COMPUTE_J(buf##_0, buf##_1, (c)*2);                              \
    COMPUTE_J(buf##_2, buf##_3, (c)*2 + 1);                          \
} while (0)

__global__ __launch_bounds__(256, 4) void main_kernel(
    const float* __restrict__ img, const float* __restrict__ loc,
    const float* __restrict__ b11, const float* __restrict__ b12,
    const float* __restrict__ b21, const float* __restrict__ ln_g,
    const float* __restrict__ ln_b, const float* __restrict__ b3,
    const __bf16* __restrict__ ws, float* __restrict__ out)
{
    // LDS carve (35328 B -> 4 blocks/CU):
    //  [0,17408)      catL [64][136] bf16 (dead after P1); overlays:
    //    [0,9216)      w12L [64][72] bf16  (written P2, read at frag load)
    //    [9216,11264)  ps   [64][4] float2 (LN partials, written P4)
    //  [17408,26624)  w11L [64][72] bf16 (last read P2) -> xL in P4/P5
    //  [26624,35328)  w21T [64 j][68 t] bf16 (transposed, read in K-loop)
    __shared__ __align__(1024) char smem[35328];
    __bf16* catL = (__bf16*)smem;
    __bf16* w12L = (__bf16*)smem;
    float2* ps   = (float2*)(smem + 9216);
    __bf16* w11L = (__bf16*)(smem + 17408);
    __bf16* xL   = w11L;
    __bf16* w21T = (__bf16*)(smem + 26624);

    const int tid  = threadIdx.x;
    const int wv   = tid >> 6;
    const int lane = tid & 63;
    const int ln   = lane & 15;     // A-row / C-col / B-col lane index
    const int quad = lane >> 4;     // k-quad / C-row group
    const int ob   = wv * 16;       // this wave's 16 o-cols (= col-group wv)
    const long tb  = (long)blockIdx.x * 64;

    const __bf16* Bt22  = ws + OFF_BT22;
    const __bf16* W11bt = ws + OFF_W11;
    const __bf16* W21bt = ws + OFF_W21;
    const __bf16* W12bt = ws + OFF_W12;
    const __bf16* W3bt  = ws + OFF_W3;

    // ---------- P0: stage cat = [img | loc] as bf16 (64 tokens) ----------
    {
        const float* srcs[2] = {img, loc};
        #pragma unroll
        for (int s = 0; s < 2; ++s) {
            const float* src = srcs[s] + tb * 64;
            #pragma unroll
            for (int it = 0; it < 4; ++it) {
                int u = (it * 256 + tid) * 4;         // 0..4092
                int t = u >> 6, c = u & 63;
                const float4 v = *(const float4*)(src + u);
                bf16x4 pk = {(__bf16)v.x, (__bf16)v.y, (__bf16)v.z, (__bf16)v.w};
                *(bf16x4*)(catL + t * 136 + s * 64 + c) = pk;
            }
        }
    }
    __syncthreads();

    // ---------- P1: wv 0,1 -> w11 cols (wv&1)*32..+32 (A-layout);
    //               wv 2,3 -> w21 cols (wv&1)*32..+32 (TRANSPOSED) ----------
    {
        const int isW21 = wv >> 1;
        const int cb0 = (wv & 1) * 32;
        const __bf16* Wbt = isW21 ? W21bt : W11bt;
        const float* bsel = isW21 ? b21 : b11;
        f32x4 a1[4][2] = {};
        #pragma unroll
        for (int kb = 0; kb < 4; ++kb) {
            bf16x8 af[4];
            #pragma unroll
            for (int mf = 0; mf < 4; ++mf)
                af[mf] = *(const bf16x8*)(catL + (mf*16 + ln)*136 + kb*32 + quad*8);
            #pragma unroll
            for (int nf = 0; nf < 2; ++nf) {
                bf16x8 bw = *(const bf16x8*)(Wbt + ((kb*4 + quad)*64 + cb0 + nf*16 + ln)*8);
                #pragma unroll
                for (int mf = 0; mf < 4; ++mf)
                    a1[mf][nf] = MFMA16(af[mf], bw, a1[mf][nf]);
            }
        }
        if (!isW21) {
            #pragma unroll
            for (int nf = 0; nf < 2; ++nf) {
                int o = cb0 + nf*16 + ln;
                float cb = bsel[o];
                #pragma unroll
                for (int mf = 0; mf < 4; ++mf)
                    #pragma unroll
                    for (int r = 0; r < 4; ++r) {
                        int t = mf*16 + quad*4 + r;
                        float v = a1[mf][nf][r] + cb; v = v > 0.f ? v : 0.f;
                        w11L[t*72 + o] = (__bf16)v;
                    }
            }
        } else {
            #pragma unroll
            for (int nf = 0; nf < 2; ++nf) {
                int o = cb0 + nf*16 + ln;
                float cb = bsel[o];
                #pragma unroll
                for (int mf = 0; mf < 4; ++mf) {
                    bf16x4 pk;
                    #pragma unroll
                    for (int r = 0; r < 4; ++r) {
                        float v = a1[mf][nf][r] + cb; v = v > 0.f ? v : 0.f;
                        pk[r] = (__bf16)v;
                    }
                    *(bf16x4*)(w21T + o*68 + mf*16 + quad*4) = pk;
                }
            }
        }
    }
    __syncthreads();

    // ---------- P2: w12 = w11@W12 + b12 (no relu); wave computes its 16 cols ----------
    // (writes w12L, which overlays dead catL)
    {
        float c12 = b12[ob + ln];
        f32x4 a12c[4] = {};
        #pragma unroll
        for (int kb = 0; kb < 2; ++kb) {
            bf16x8 bw = *(const bf16x8*)(W12bt + ((kb*4 + quad)*64 + ob + ln)*8);
            #pragma unroll
            for (int mf = 0; mf < 4; ++mf) {
                bf16x8 af = *(const bf16x8*)(w11L + (mf*16 + ln)*72 + kb*32 + quad*8);
                a12c[mf] = MFMA16(af, bw, a12c[mf]);
            }
        }
        #pragma unroll
        for (int mf = 0; mf < 4; ++mf)
            #pragma unroll
            for (int r = 0; r < 4; ++r) {
                int t = mf*16 + quad*4 + r;
                w12L[t*72 + ob + ln] = (__bf16)(a12c[mf][r] + c12);
            }
    }
    __syncthreads();

    // w12 A-fragments: constant MFMA A-operand for the whole K-loop (and the
    // bias-block A directly). Full 64-k rows per token, 64 tokens/wave.
    bf16x8 a12[4][2];
    #pragma unroll
    for (int mf = 0; mf < 4; ++mf)
        #pragma unroll
        for (int sub = 0; sub < 2; ++sub)
            a12[mf][sub] = *(const bf16x8*)(w12L + (mf*16 + ln)*72 + sub*32 + quad*8);

    // ---------- P3: barrier-free K-loop, named VGPR double-buffer ----------
    // fragment (c, s): k8 = c*16 + s*4 + quad -> one contiguous 1 KB wave-load.
    const __bf16* Bw = Bt22 + ((long)wv * 520 + quad) * 128 + ln * 8;

    bf16x8 B0_0, B0_1, B0_2, B0_3;
    bf16x8 B1_0, B1_1, B1_2, B1_3;

    f32x4 acc[4] = {};
    LOADCH(B0, 0);
    #pragma unroll 1
    for (int cc = 0; cc < 32; cc += 2) {
        LOADCH(B1, cc + 1);
        COMPUTE(B0, cc);
        if (cc + 2 < 32) LOADCH(B0, cc + 2);
        COMPUTE(B1, cc + 1);
    }
    // bias rows: A = w12 directly, weight 1 (frags loaded now, buffers dead)
    {
        bf16x8 bb0 = *(const bf16x8*)(Bw + (512 + 0) * 128);
        bf16x8 bb1 = *(const bf16x8*)(Bw + (512 + 4) * 128);
        #pragma unroll
        for (int mf = 0; mf < 4; ++mf) {
            acc[mf] = MFMA16(a12[mf][0], bb0, acc[mf]);
            acc[mf] = MFMA16(a12[mf][1], bb1, acc[mf]);
        }
    }

    // ---------- P4: LayerNorm(64) + relu (cols split 16/wave -> LDS partials) ----------
    #pragma unroll
    for (int mf = 0; mf < 4; ++mf)
        #pragma unroll
        for (int r = 0; r < 4; ++r) {
            float v = acc[mf][r];
            float s1 = v, s2 = v*v;
            #pragma unroll
            for (int d = 1; d < 16; d <<= 1) {   // reduce this quad's 16 lanes
                s1 += __shfl_xor(s1, d, 64);
                s2 += __shfl_xor(s2, d, 64);
            }
            if (ln == 0) {
                int t = mf*16 + quad*4 + r;
                ps[t*4 + wv] = make_float2(s1, s2);
            }
        }
    __syncthreads();

    float gv = ln_g[ob + ln], bv = ln_b[ob + ln], b3v = b3[ob + ln];
    #pragma unroll
    for (int mf = 0; mf < 4; ++mf)
        #pragma unroll
        for (int r = 0; r < 4; ++r) {
            int t = mf*16 + quad*4 + r;
            float2 p0 = ps[t*4], p1 = ps[t*4 + 1], p2 = ps[t*4 + 2], p3 = ps[t*4 + 3];
            float mean = (p0.x + p1.x + p2.x + p3.x) * 0.015625f;
            float var  = (p0.y + p1.y + p2.y + p3.y) * 0.015625f - mean * mean;
            float inv  = rsqrtf(var + 1e-5f);
            float v = (acc[mf][r] - mean) * inv * gv + bv;
            v = v > 0.f ? v : 0.f;
            xL[t*72 + ob + ln] = (__bf16)v;
        }
    __syncthreads();

    // ---------- P5: out = x @ W3 + b3 (16 cols per wave, 64 tokens) ----------
    f32x4 a3[4] = {};
    #pragma unroll
    for (int kb = 0; kb < 2; ++kb) {
        bf16x8 bfr = *(const bf16x8*)(W3bt + ((kb*4 + quad)*64 + ob + ln)*8);
        #pragma unroll
        for (int mf = 0; mf < 4; ++mf) {
            bf16x8 af = *(const bf16x8*)(xL + (mf*16 + ln)*72 + kb*32 + quad*8);
            a3[mf] = MFMA16(af, bfr, a3[mf]);
        }
    }
    #pragma unroll
    for (int mf = 0; mf < 4; ++mf)
        #pragma unroll
        for (int r = 0; r < 4; ++r) {
            long t = tb + mf*16 + quad*4 + r;
            out[t*64 + ob + ln] = a3[mf][r] + b3v;
        }
}

extern "C" void kernel_launch(void* const* d_in, const int* in_sizes, int n_in,
                              void* d_out, int out_size, void* d_ws, size_t ws_size,
                              hipStream_t stream)
{
    const float* img  = (const float*)d_in[0];
    const float* loc  = (const float*)d_in[1];
    const float* W11  = (const float*)d_in[2];
    const float* b11  = (const float*)d_in[3];
    const float* W12  = (const float*)d_in[4];
    const float* b12  = (const float*)d_in[5];
    const float* W21  = (const float*)d_in[6];
    const float* b21  = (const float*)d_in[7];
    const float* W22  = (const float*)d_in[8];
    const float* b22  = (const float*)d_in[9];
    const float* ln_g = (const float*)d_in[10];
    const float* ln_b = (const float*)d_in[11];
    const float* W3   = (const float*)d_in[12];
    const float* b3   = (const float*)d_in[13];
    __bf16* ws = (__bf16*)d_ws;
    float*  o  = (float*)d_out;

    prep_kernel<<<71, 256, 0, stream>>>(W22, b22, W11, W21, W12, W3, ws);
    main_kernel<<<512, 256, 0, stream>>>(img, loc, b11, b12, b21, ln_g, ln_b, b3, ws, o);
}

// Round 14
// 116.944 us; speedup vs baseline: 1.4820x; 1.4820x over previous
//
#include <hip/hip_runtime.h>
#include <cstdint>

// Dynamic_MLP_C: fused bf16-MFMA implementation.
//
// Reformulation: x[t,o] = sum_k A[t,k] * B[k,o],  k = j*64+i  (K = 4160)
//   A[t, j*64+i] = w21[t,j] * w12[t,i]  (rank-1), bias rows A[t,4096+i]=w12[t,i].
// Re-association: x[t,o] = sum_j w21[t,j] * (w12[t,:] @ B_j)[o]
//   -> A-fragment = CONSTANT w12 regs; per j: 2 MFMAs -> m; acc += w21[t,j]*m.
//
// R7-R13 history: barrier-free K-loop reading B (532 KB, L2-resident) straight
// into named VGPR buffers. R9 (mf=4, launch_bounds(256,2)): VGPR=88, NO spill,
// but 46.6 KB LDS -> 3 blocks/CU. R13 tried 4 blocks/CU via launch_bounds(256,4)
// -> allocator pinned to 64 VGPR -> respill (WRITE 162 MB, 88 us).
// R14 = R13's 35.3 KB LDS overlay + R9's (256,2): VGPR~88 allows 5 waves/SIMD,
// LDS allows 4 blocks/CU -> HW picks 4 blocks/CU with R9's 272 MB traffic.

typedef __bf16 bf16x4 __attribute__((ext_vector_type(4)));
typedef __bf16 bf16x8 __attribute__((ext_vector_type(8)));
typedef float  f32x4  __attribute__((ext_vector_type(4)));

#define MFMA16(A, B, C) __builtin_amdgcn_mfma_f32_16x16x32_bf16(A, B, C, 0, 0, 0)

// workspace element offsets (bf16 elements)
#define OFF_BT22 0         // K=4160 grouped layout, 266240 elems
#define OFF_W11  266240    // K=128,  8192 (frag layout)
#define OFF_W21  274432    // K=128,  8192
#define OFF_W12  282624    // K=64,   4096
#define OFF_W3   286720    // K=64,   4096

// prep: [64 k x 64 o] fp32 tile -> bf16.
//  W22/b22 tiles: grouped layout ws[((o>>4)*520 + k8)*128 + (o&15)*8 + (k&7)]
//  small weights: frag layout    ws[base + (k>>3)*512 + o*8 + (k&7)]
__global__ __launch_bounds__(256) void prep_kernel(
    const float* __restrict__ W22, const float* __restrict__ b22,
    const float* __restrict__ W11, const float* __restrict__ W21,
    const float* __restrict__ W12, const float* __restrict__ W3,
    __bf16* __restrict__ ws)
{
    __shared__ __bf16 T[64][72];
    const int b = blockIdx.x, tid = threadIdx.x;
    const float* src; long base = 0;
    if (b < 64)       { src = W22 + b * 4096; }
    else if (b == 64) { src = b22; }
    else if (b < 67)  { src = W11 + (b - 65) * 4096; base = OFF_W11 + (b - 65) * 4096; }
    else if (b < 69)  { src = W21 + (b - 67) * 4096; base = OFF_W21 + (b - 67) * 4096; }
    else if (b == 69) { src = W12;                   base = OFF_W12; }
    else              { src = W3;                    base = OFF_W3; }
    #pragma unroll
    for (int it = 0; it < 4; ++it) {
        int u = it * 1024 + tid * 4;
        int r = u >> 6, c = u & 63;
        const float4 v = *(const float4*)(src + u);
        T[r][c] = (__bf16)v.x; T[r][c + 1] = (__bf16)v.y;
        T[r][c + 2] = (__bf16)v.z; T[r][c + 3] = (__bf16)v.w;
    }
    __syncthreads();
    #pragma unroll
    for (int it = 0; it < 2; ++it) {
        int item = it * 256 + tid;
        int q = item >> 6, o = item & 63;
        bf16x8 pk;
        #pragma unroll
        for (int kj = 0; kj < 8; ++kj) pk[kj] = T[q * 8 + kj][o];
        long dstE;
        if (b <= 64) {
            int k8 = (b == 64 ? 512 : b * 8) + q;
            dstE = OFF_BT22 + ((long)(o >> 4) * 520 + k8) * 128 + (o & 15) * 8;
        } else {
            dstE = base + q * 512 + o * 8;
        }
        *(bf16x8*)(ws + dstE) = pk;
    }
}

// ---- register chunk-buffer machinery: named registers, token-pasted ----
#define LOADCH(buf, c) do {                                          \
    buf##_0 = *(const bf16x8*)(Bw + ((c)*16 +  0) * 128);            \
    buf##_1 = *(const bf16x8*)(Bw + ((c)*16 +  4) * 128);            \
    buf##_2 = *(const bf16x8*)(Bw + ((c)*16 +  8) * 128);            \
    buf##_3 = *(const bf16x8*)(Bw + ((c)*16 + 12) * 128);            \
} while (0)

#define COMPUTE_J(b0, b1, j) do {                                    \
    f32x4 w4[4];                                                     \
    _Pragma("unroll")                                                \
    for (int mf = 0; mf < 4; ++mf) {                                 \
        bf16x4 wv4 = *(const bf16x4*)(w21T + (j)*68 + mf*16 + quad*4);\
        w4[mf] = __builtin_convertvector(wv4, f32x4);                \
    }                                                                \
    _Pragma("unroll")                                                \
    for (int mf = 0; mf < 4; ++mf) {                                 \
        f32x4 fz = {};                                               \
        f32x4 m = MFMA16(a12[mf][0], b0, fz);                        \
        m       = MFMA16(a12[mf][1], b1, m);                         \
        _Pragma("unroll")                                            \
        for (int r = 0; r < 4; ++r)                                  \
            acc[mf][r] = fmaf(w4[mf][r], m[r], acc[mf][r]);          \
    }                                                                \
} while (0)

#define COMPUTE(buf, c) do {                                         \
    COMPUTE_J(buf##_0, buf##_1, (c)*2);                              \
    COMPUTE_J(buf##_2, buf##_3, (c)*2 + 1);                          \
} while (0)

__global__ __launch_bounds__(256, 2) void main_kernel(
    const float* __restrict__ img, const float* __restrict__ loc,
    const float* __restrict__ b11, const float* __restrict__ b12,
    const float* __restrict__ b21, const float* __restrict__ ln_g,
    const float* __restrict__ ln_b, const float* __restrict__ b3,
    const __bf16* __restrict__ ws, float* __restrict__ out)
{
    // LDS carve (35328 B; with VGPR~88 the HW fits 4 blocks/CU):
    //  [0,17408)      catL [64][136] bf16 (dead after P1); overlays:
    //    [0,9216)      w12L [64][72] bf16  (written P2, read at frag load)
    //    [9216,11264)  ps   [64][4] float2 (LN partials, written P4)
    //  [17408,26624)  w11L [64][72] bf16 (last read P2) -> xL in P4/P5
    //  [26624,35328)  w21T [64 j][68 t] bf16 (transposed, read in K-loop)
    __shared__ __align__(1024) char smem[35328];
    __bf16* catL = (__bf16*)smem;
    __bf16* w12L = (__bf16*)smem;
    float2* ps   = (float2*)(smem + 9216);
    __bf16* w11L = (__bf16*)(smem + 17408);
    __bf16* xL   = w11L;
    __bf16* w21T = (__bf16*)(smem + 26624);

    const int tid  = threadIdx.x;
    const int wv   = tid >> 6;
    const int lane = tid & 63;
    const int ln   = lane & 15;     // A-row / C-col / B-col lane index
    const int quad = lane >> 4;     // k-quad / C-row group
    const int ob   = wv * 16;       // this wave's 16 o-cols (= col-group wv)
    const long tb  = (long)blockIdx.x * 64;

    const __bf16* Bt22  = ws + OFF_BT22;
    const __bf16* W11bt = ws + OFF_W11;
    const __bf16* W21bt = ws + OFF_W21;
    const __bf16* W12bt = ws + OFF_W12;
    const __bf16* W3bt  = ws + OFF_W3;

    // ---------- P0: stage cat = [img | loc] as bf16 (64 tokens) ----------
    {
        const float* srcs[2] = {img, loc};
        #pragma unroll
        for (int s = 0; s < 2; ++s) {
            const float* src = srcs[s] + tb * 64;
            #pragma unroll
            for (int it = 0; it < 4; ++it) {
                int u = (it * 256 + tid) * 4;         // 0..4092
                int t = u >> 6, c = u & 63;
                const float4 v = *(const float4*)(src + u);
                bf16x4 pk = {(__bf16)v.x, (__bf16)v.y, (__bf16)v.z, (__bf16)v.w};
                *(bf16x4*)(catL + t * 136 + s * 64 + c) = pk;
            }
        }
    }
    __syncthreads();

    // ---------- P1: wv 0,1 -> w11 cols (wv&1)*32..+32 (A-layout);
    //               wv 2,3 -> w21 cols (wv&1)*32..+32 (TRANSPOSED) ----------
    {
        const int isW21 = wv >> 1;
        const int cb0 = (wv & 1) * 32;
        const __bf16* Wbt = isW21 ? W21bt : W11bt;
        const float* bsel = isW21 ? b21 : b11;
        f32x4 a1[4][2] = {};
        #pragma unroll
        for (int kb = 0; kb < 4; ++kb) {
            bf16x8 af[4];
            #pragma unroll
            for (int mf = 0; mf < 4; ++mf)
                af[mf] = *(const bf16x8*)(catL + (mf*16 + ln)*136 + kb*32 + quad*8);
            #pragma unroll
            for (int nf = 0; nf < 2; ++nf) {
                bf16x8 bw = *(const bf16x8*)(Wbt + ((kb*4 + quad)*64 + cb0 + nf*16 + ln)*8);
                #pragma unroll
                for (int mf = 0; mf < 4; ++mf)
                    a1[mf][nf] = MFMA16(af[mf], bw, a1[mf][nf]);
            }
        }
        if (!isW21) {
            #pragma unroll
            for (int nf = 0; nf < 2; ++nf) {
                int o = cb0 + nf*16 + ln;
                float cb = bsel[o];
                #pragma unroll
                for (int mf = 0; mf < 4; ++mf)
                    #pragma unroll
                    for (int r = 0; r < 4; ++r) {
                        int t = mf*16 + quad*4 + r;
                        float v = a1[mf][nf][r] + cb; v = v > 0.f ? v : 0.f;
                        w11L[t*72 + o] = (__bf16)v;
                    }
            }
        } else {
            #pragma unroll
            for (int nf = 0; nf < 2; ++nf) {
                int o = cb0 + nf*16 + ln;
                float cb = bsel[o];
                #pragma unroll
                for (int mf = 0; mf < 4; ++mf) {
                    bf16x4 pk;
                    #pragma unroll
                    for (int r = 0; r < 4; ++r) {
                        float v = a1[mf][nf][r] + cb; v = v > 0.f ? v : 0.f;
                        pk[r] = (__bf16)v;
                    }
                    *(bf16x4*)(w21T + o*68 + mf*16 + quad*4) = pk;
                }
            }
        }
    }
    __syncthreads();

    // ---------- P2: w12 = w11@W12 + b12 (no relu); wave computes its 16 cols ----------
    // (writes w12L, which overlays dead catL)
    {
        float c12 = b12[ob + ln];
        f32x4 a12c[4] = {};
        #pragma unroll
        for (int kb = 0; kb < 2; ++kb) {
            bf16x8 bw = *(const bf16x8*)(W12bt + ((kb*4 + quad)*64 + ob + ln)*8);
            #pragma unroll
            for (int mf = 0; mf < 4; ++mf) {
                bf16x8 af = *(const bf16x8*)(w11L + (mf*16 + ln)*72 + kb*32 + quad*8);
                a12c[mf] = MFMA16(af, bw, a12c[mf]);
            }
        }
        #pragma unroll
        for (int mf = 0; mf < 4; ++mf)
            #pragma unroll
            for (int r = 0; r < 4; ++r) {
                int t = mf*16 + quad*4 + r;
                w12L[t*72 + ob + ln] = (__bf16)(a12c[mf][r] + c12);
            }
    }
    __syncthreads();

    // w12 A-fragments: constant MFMA A-operand for the whole K-loop (and the
    // bias-block A directly). Full 64-k rows per token, 64 tokens/wave.
    bf16x8 a12[4][2];
    #pragma unroll
    for (int mf = 0; mf < 4; ++mf)
        #pragma unroll
        for (int sub = 0; sub < 2; ++sub)
            a12[mf][sub] = *(const bf16x8*)(w12L + (mf*16 + ln)*72 + sub*32 + quad*8);

    // ---------- P3: barrier-free K-loop, named VGPR double-buffer ----------
    // fragment (c, s): k8 = c*16 + s*4 + quad -> one contiguous 1 KB wave-load.
    const __bf16* Bw = Bt22 + ((long)wv * 520 + quad) * 128 + ln * 8;

    bf16x8 B0_0, B0_1, B0_2, B0_3;
    bf16x8 B1_0, B1_1, B1_2, B1_3;

    f32x4 acc[4] = {};
    LOADCH(B0, 0);
    #pragma unroll 1
    for (int cc = 0; cc < 32; cc += 2) {
        LOADCH(B1, cc + 1);
        COMPUTE(B0, cc);
        if (cc + 2 < 32) LOADCH(B0, cc + 2);
        COMPUTE(B1, cc + 1);
    }
    // bias rows: A = w12 directly, weight 1 (frags loaded now, buffers dead)
    {
        bf16x8 bb0 = *(const bf16x8*)(Bw + (512 + 0) * 128);
        bf16x8 bb1 = *(const bf16x8*)(Bw + (512 + 4) * 128);
        #pragma unroll
        for (int mf = 0; mf < 4; ++mf) {
            acc[mf] = MFMA16(a12[mf][0], bb0, acc[mf]);
            acc[mf] = MFMA16(a12[mf][1], bb1, acc[mf]);
        }
    }

    // ---------- P4: LayerNorm(64) + relu (cols split 16/wave -> LDS partials) ----------
    #pragma unroll
    for (int mf = 0; mf < 4; ++mf)
        #pragma unroll
        for (int r = 0; r < 4; ++r) {
            float v = acc[mf][r];
            float s1 = v, s2 = v*v;
            #pragma unroll
            for (int d = 1; d < 16; d <<= 1) {   // reduce this quad's 16 lanes
                s1 += __shfl_xor(s1, d, 64);
                s2 += __shfl_xor(s2, d, 64);
            }
            if (ln == 0) {
                int t = mf*16 + quad*4 + r;
                ps[t*4 + wv] = make_float2(s1, s2);
            }
        }
    __syncthreads();

    float gv = ln_g[ob + ln], bv = ln_b[ob + ln], b3v = b3[ob + ln];
    #pragma unroll
    for (int mf = 0; mf < 4; ++mf)
        #pragma unroll
        for (int r = 0; r < 4; ++r) {
            int t = mf*16 + quad*4 + r;
            float2 p0 = ps[t*4], p1 = ps[t*4 + 1], p2 = ps[t*4 + 2], p3 = ps[t*4 + 3];
            float mean = (p0.x + p1.x + p2.x + p3.x) * 0.015625f;
            float var  = (p0.y + p1.y + p2.y + p3.y) * 0.015625f - mean * mean;
            float inv  = rsqrtf(var + 1e-5f);
            float v = (acc[mf][r] - mean) * inv * gv + bv;
            v = v > 0.f ? v : 0.f;
            xL[t*72 + ob + ln] = (__bf16)v;
        }
    __syncthreads();

    // ---------- P5: out = x @ W3 + b3 (16 cols per wave, 64 tokens) ----------
    f32x4 a3[4] = {};
    #pragma unroll
    for (int kb = 0; kb < 2; ++kb) {
        bf16x8 bfr = *(const bf16x8*)(W3bt + ((kb*4 + quad)*64 + ob + ln)*8);
        #pragma unroll
        for (int mf = 0; mf < 4; ++mf) {
            bf16x8 af = *(const bf16x8*)(xL + (mf*16 + ln)*72 + kb*32 + quad*8);
            a3[mf] = MFMA16(af, bfr, a3[mf]);
        }
    }
    #pragma unroll
    for (int mf = 0; mf < 4; ++mf)
        #pragma unroll
        for (int r = 0; r < 4; ++r) {
            long t = tb + mf*16 + quad*4 + r;
            out[t*64 + ob + ln] = a3[mf][r] + b3v;
        }
}

extern "C" void kernel_launch(void* const* d_in, const int* in_sizes, int n_in,
                              void* d_out, int out_size, void* d_ws, size_t ws_size,
                              hipStream_t stream)
{
    const float* img  = (const float*)d_in[0];
    const float* loc  = (const float*)d_in[1];
    const float* W11  = (const float*)d_in[2];
    const float* b11  = (const float*)d_in[3];
    const float* W12  = (const float*)d_in[4];
    const float* b12  = (const float*)d_in[5];
    const float* W21  = (const float*)d_in[6];
    const float* b21  = (const float*)d_in[7];
    const float* W22  = (const float*)d_in[8];
    const float* b22  = (const float*)d_in[9];
    const float* ln_g = (const float*)d_in[10];
    const float* ln_b = (const float*)d_in[11];
    const float* W3   = (const float*)d_in[12];
    const float* b3   = (const float*)d_in[13];
    __bf16* ws = (__bf16*)d_ws;
    float*  o  = (float*)d_out;

    prep_kernel<<<71, 256, 0, stream>>>(W22, b22, W11, W21, W12, W3, ws);
    main_kernel<<<512, 256, 0, stream>>>(img, loc, b11, b12, b21, ln_g, ln_b, b3, ws, o);
}

// Round 15
// 115.511 us; speedup vs baseline: 1.5004x; 1.0124x over previous
//
#include <hip/hip_runtime.h>
#include <cstdint>

// Dynamic_MLP_C: fused bf16-MFMA implementation.
//
// Reformulation: x[t,o] = sum_k A[t,k] * B[k,o],  k = j*64+i  (K = 4160)
//   A[t, j*64+i] = w21[t,j] * w12[t,i]  (rank-1), bias rows A[t,4096+i]=w12[t,i].
// Re-association: x[t,o] = sum_j w21[t,j] * (w12[t,:] @ B_j)[o]
//   -> A-fragment = CONSTANT w12 regs; per j: 2 MFMAs -> m; acc += w21[t,j]*m.
//
// R7-R14: barrier-free K-loop, B (532 KB, L2-resident) -> named VGPR buffers.
// R14 post-mortem: main pinned at ~32 us across all occupancy/traffic configs.
// Model that fits: per-CU L2 link ~64 B/cyc; per-CU B traffic = blocks/CU x
// 532 KB (R9 1.6 MB, R12/R14 2.1 MB -> 11-16 us link time + latency).
// R15: cut per-CU traffic with fewer, bigger blocks: grid 256 x block 512
// (8 waves = 2 token-halves x 4 o-groups, 128 tok) -> ~1 block/CU ->
// 1.06 MB/CU (pair-shared o-slices), half of R14. K-loop per wave identical
// to R14's proven no-spill mf=4 (~88 VGPR; launch_bounds(512,2) = 256 budget).

typedef __bf16 bf16x4 __attribute__((ext_vector_type(4)));
typedef __bf16 bf16x8 __attribute__((ext_vector_type(8)));
typedef float  f32x4  __attribute__((ext_vector_type(4)));

#define MFMA16(A, B, C) __builtin_amdgcn_mfma_f32_16x16x32_bf16(A, B, C, 0, 0, 0)

// workspace element offsets (bf16 elements)
#define OFF_BT22 0         // K=4160 grouped layout, 266240 elems
#define OFF_W11  266240    // K=128,  8192 (frag layout)
#define OFF_W21  274432    // K=128,  8192
#define OFF_W12  282624    // K=64,   4096
#define OFF_W3   286720    // K=64,   4096

// prep: [64 k x 64 o] fp32 tile -> bf16.
//  W22/b22 tiles: grouped layout ws[((o>>4)*520 + k8)*128 + (o&15)*8 + (k&7)]
//  small weights: frag layout    ws[base + (k>>3)*512 + o*8 + (k&7)]
__global__ __launch_bounds__(256) void prep_kernel(
    const float* __restrict__ W22, const float* __restrict__ b22,
    const float* __restrict__ W11, const float* __restrict__ W21,
    const float* __restrict__ W12, const float* __restrict__ W3,
    __bf16* __restrict__ ws)
{
    __shared__ __bf16 T[64][72];
    const int b = blockIdx.x, tid = threadIdx.x;
    const float* src; long base = 0;
    if (b < 64)       { src = W22 + b * 4096; }
    else if (b == 64) { src = b22; }
    else if (b < 67)  { src = W11 + (b - 65) * 4096; base = OFF_W11 + (b - 65) * 4096; }
    else if (b < 69)  { src = W21 + (b - 67) * 4096; base = OFF_W21 + (b - 67) * 4096; }
    else if (b == 69) { src = W12;                   base = OFF_W12; }
    else              { src = W3;                    base = OFF_W3; }
    #pragma unroll
    for (int it = 0; it < 4; ++it) {
        int u = it * 1024 + tid * 4;
        int r = u >> 6, c = u & 63;
        const float4 v = *(const float4*)(src + u);
        T[r][c] = (__bf16)v.x; T[r][c + 1] = (__bf16)v.y;
        T[r][c + 2] = (__bf16)v.z; T[r][c + 3] = (__bf16)v.w;
    }
    __syncthreads();
    #pragma unroll
    for (int it = 0; it < 2; ++it) {
        int item = it * 256 + tid;
        int q = item >> 6, o = item & 63;
        bf16x8 pk;
        #pragma unroll
        for (int kj = 0; kj < 8; ++kj) pk[kj] = T[q * 8 + kj][o];
        long dstE;
        if (b <= 64) {
            int k8 = (b == 64 ? 512 : b * 8) + q;
            dstE = OFF_BT22 + ((long)(o >> 4) * 520 + k8) * 128 + (o & 15) * 8;
        } else {
            dstE = base + q * 512 + o * 8;
        }
        *(bf16x8*)(ws + dstE) = pk;
    }
}

// ---- register chunk-buffer machinery: named registers, token-pasted ----
#define LOADCH(buf, c) do {                                          \
    buf##_0 = *(const bf16x8*)(Bw + ((c)*16 +  0) * 128);            \
    buf##_1 = *(const bf16x8*)(Bw + ((c)*16 +  4) * 128);            \
    buf##_2 = *(const bf16x8*)(Bw + ((c)*16 +  8) * 128);            \
    buf##_3 = *(const bf16x8*)(Bw + ((c)*16 + 12) * 128);            \
} while (0)

#define COMPUTE_J(b0, b1, j) do {                                    \
    f32x4 w4[4];                                                     \
    _Pragma("unroll")                                                \
    for (int mf = 0; mf < 4; ++mf) {                                 \
        bf16x4 wv4 = *(const bf16x4*)(w21T + (j)*132 + wt + mf*16 + quad*4);\
        w4[mf] = __builtin_convertvector(wv4, f32x4);                \
    }                                                                \
    _Pragma("unroll")                                                \
    for (int mf = 0; mf < 4; ++mf) {                                 \
        f32x4 fz = {};                                               \
        f32x4 m = MFMA16(a12[mf][0], b0, fz);                        \
        m       = MFMA16(a12[mf][1], b1, m);                         \
        _Pragma("unroll")                                            \
        for (int r = 0; r < 4; ++r)                                  \
            acc[mf][r] = fmaf(w4[mf][r], m[r], acc[mf][r]);          \
    }                                                                \
} while (0)

#define COMPUTE(buf, c) do {                                         \
    COMPUTE_J(buf##_0, buf##_1, (c)*2);                              \
    COMPUTE_J(buf##_2, buf##_3, (c)*2 + 1);                          \
} while (0)

__global__ __launch_bounds__(512, 2) void main_kernel(
    const float* __restrict__ img, const float* __restrict__ loc,
    const float* __restrict__ b11, const float* __restrict__ b12,
    const float* __restrict__ b21, const float* __restrict__ ln_g,
    const float* __restrict__ ln_b, const float* __restrict__ b3,
    const __bf16* __restrict__ ws, float* __restrict__ out)
{
    // 512 threads = 8 waves: wv = [og(2b)|th(1b)] -> th = wv&1 token half,
    // og = wv>>1 o-group. Wave = 64 tokens x 16 cols (mf=4, R14's K-loop).
    // LDS carve (70144 B, ~1 block/CU at grid 256):
    //  [0,34816)      catL [128][136] bf16 (dead after P1); overlays:
    //    [0,18432)     w12L [128][72] bf16  (written P2, read at frag load)
    //    [18432,22528) ps   [128][4] float2 (LN partials, written P4)
    //  [34816,53248)  w11L [128][72] bf16 (last read P2) -> xL in P4/P5
    //  [53248,70144)  w21T [64 j][132 t] bf16 (transposed, read in K-loop)
    __shared__ __align__(1024) char smem[70144];
    __bf16* catL = (__bf16*)smem;
    __bf16* w12L = (__bf16*)smem;
    float2* ps   = (float2*)(smem + 18432);
    __bf16* w11L = (__bf16*)(smem + 34816);
    __bf16* xL   = w11L;
    __bf16* w21T = (__bf16*)(smem + 53248);

    const int tid  = threadIdx.x;
    const int wv   = tid >> 6;
    const int lane = tid & 63;
    const int ln   = lane & 15;     // A-row / C-col / B-col lane index
    const int quad = lane >> 4;     // k-quad / C-row group
    const int th   = wv & 1;        // token half
    const int og   = wv >> 1;       // o-group (16 cols)
    const int wt   = th * 64;       // block-local token base of this wave
    const int ob   = og * 16;       // o-col base
    const long tb  = (long)blockIdx.x * 128;

    const __bf16* Bt22  = ws + OFF_BT22;
    const __bf16* W11bt = ws + OFF_W11;
    const __bf16* W21bt = ws + OFF_W21;
    const __bf16* W12bt = ws + OFF_W12;
    const __bf16* W3bt  = ws + OFF_W3;

    // ---------- P0: stage cat = [img | loc] as bf16 (128 tokens) ----------
    {
        const float* srcs[2] = {img, loc};
        #pragma unroll
        for (int s = 0; s < 2; ++s) {
            const float* src = srcs[s] + tb * 64;
            #pragma unroll
            for (int it = 0; it < 4; ++it) {
                int u = (it * 512 + tid) * 4;         // 0..8188
                int t = u >> 6, c = u & 63;
                const float4 v = *(const float4*)(src + u);
                bf16x4 pk = {(__bf16)v.x, (__bf16)v.y, (__bf16)v.z, (__bf16)v.w};
                *(bf16x4*)(catL + t * 136 + s * 64 + c) = pk;
            }
        }
    }
    __syncthreads();

    // ---------- P1: waves 0-3 -> w11 (A-layout), waves 4-7 -> w21 (TRANSPOSED).
    // Within each group of 4: covers (token half) x (32-col half). ----------
    {
        const int isW21 = wv >> 2;
        const int w     = wv & 3;
        const int th1   = w >> 1;            // token half this wave computes
        const int cb0   = (w & 1) * 32;      // col half
        const int wt1   = th1 * 64;
        const __bf16* Wbt = isW21 ? W21bt : W11bt;
        const float* bsel = isW21 ? b21 : b11;
        f32x4 a1[4][2] = {};
        #pragma unroll
        for (int kb = 0; kb < 4; ++kb) {
            bf16x8 af[4];
            #pragma unroll
            for (int mf = 0; mf < 4; ++mf)
                af[mf] = *(const bf16x8*)(catL + (wt1 + mf*16 + ln)*136 + kb*32 + quad*8);
            #pragma unroll
            for (int nf = 0; nf < 2; ++nf) {
                bf16x8 bw = *(const bf16x8*)(Wbt + ((kb*4 + quad)*64 + cb0 + nf*16 + ln)*8);
                #pragma unroll
                for (int mf = 0; mf < 4; ++mf)
                    a1[mf][nf] = MFMA16(af[mf], bw, a1[mf][nf]);
            }
        }
        if (!isW21) {
            #pragma unroll
            for (int nf = 0; nf < 2; ++nf) {
                int o = cb0 + nf*16 + ln;
                float cb = bsel[o];
                #pragma unroll
                for (int mf = 0; mf < 4; ++mf)
                    #pragma unroll
                    for (int r = 0; r < 4; ++r) {
                        int t = wt1 + mf*16 + quad*4 + r;
                        float v = a1[mf][nf][r] + cb; v = v > 0.f ? v : 0.f;
                        w11L[t*72 + o] = (__bf16)v;
                    }
            }
        } else {
            #pragma unroll
            for (int nf = 0; nf < 2; ++nf) {
                int o = cb0 + nf*16 + ln;
                float cb = bsel[o];
                #pragma unroll
                for (int mf = 0; mf < 4; ++mf) {
                    bf16x4 pk;
                    #pragma unroll
                    for (int r = 0; r < 4; ++r) {
                        float v = a1[mf][nf][r] + cb; v = v > 0.f ? v : 0.f;
                        pk[r] = (__bf16)v;
                    }
                    *(bf16x4*)(w21T + o*132 + wt1 + mf*16 + quad*4) = pk;
                }
            }
        }
    }
    __syncthreads();

    // ---------- P2: w12 = w11@W12 + b12 (no relu); wave = its 64 tok x 16 cols ----------
    // (writes w12L, which overlays dead catL)
    {
        float c12 = b12[ob + ln];
        f32x4 a12c[4] = {};
        #pragma unroll
        for (int kb = 0; kb < 2; ++kb) {
            bf16x8 bw = *(const bf16x8*)(W12bt + ((kb*4 + quad)*64 + ob + ln)*8);
            #pragma unroll
            for (int mf = 0; mf < 4; ++mf) {
                bf16x8 af = *(const bf16x8*)(w11L + (wt + mf*16 + ln)*72 + kb*32 + quad*8);
                a12c[mf] = MFMA16(af, bw, a12c[mf]);
            }
        }
        #pragma unroll
        for (int mf = 0; mf < 4; ++mf)
            #pragma unroll
            for (int r = 0; r < 4; ++r) {
                int t = wt + mf*16 + quad*4 + r;
                w12L[t*72 + ob + ln] = (__bf16)(a12c[mf][r] + c12);
            }
    }
    __syncthreads();

    // w12 A-fragments: constant MFMA A-operand for the whole K-loop (and the
    // bias-block A directly). Full 64-k rows per token, 64 tokens/wave.
    bf16x8 a12[4][2];
    #pragma unroll
    for (int mf = 0; mf < 4; ++mf)
        #pragma unroll
        for (int sub = 0; sub < 2; ++sub)
            a12[mf][sub] = *(const bf16x8*)(w12L + (wt + mf*16 + ln)*72 + sub*32 + quad*8);

    // ---------- P3: barrier-free K-loop, named VGPR double-buffer ----------
    // fragment (c, s): k8 = c*16 + s*4 + quad -> one contiguous 1 KB wave-load.
    const __bf16* Bw = Bt22 + ((long)og * 520 + quad) * 128 + ln * 8;

    bf16x8 B0_0, B0_1, B0_2, B0_3;
    bf16x8 B1_0, B1_1, B1_2, B1_3;

    f32x4 acc[4] = {};
    LOADCH(B0, 0);
    #pragma unroll 1
    for (int cc = 0; cc < 32; cc += 2) {
        LOADCH(B1, cc + 1);
        COMPUTE(B0, cc);
        if (cc + 2 < 32) LOADCH(B0, cc + 2);
        COMPUTE(B1, cc + 1);
    }
    // bias rows: A = w12 directly, weight 1 (frags loaded now, buffers dead)
    {
        bf16x8 bb0 = *(const bf16x8*)(Bw + (512 + 0) * 128);
        bf16x8 bb1 = *(const bf16x8*)(Bw + (512 + 4) * 128);
        #pragma unroll
        for (int mf = 0; mf < 4; ++mf) {
            acc[mf] = MFMA16(a12[mf][0], bb0, acc[mf]);
            acc[mf] = MFMA16(a12[mf][1], bb1, acc[mf]);
        }
    }

    // ---------- P4: LayerNorm(64) + relu (cols split 16/wave -> LDS partials) ----------
    #pragma unroll
    for (int mf = 0; mf < 4; ++mf)
        #pragma unroll
        for (int r = 0; r < 4; ++r) {
            float v = acc[mf][r];
            float s1 = v, s2 = v*v;
            #pragma unroll
            for (int d = 1; d < 16; d <<= 1) {   // reduce this quad's 16 lanes
                s1 += __shfl_xor(s1, d, 64);
                s2 += __shfl_xor(s2, d, 64);
            }
            if (ln == 0) {
                int t = wt + mf*16 + quad*4 + r;
                ps[t*4 + og] = make_float2(s1, s2);
            }
        }
    __syncthreads();

    float gv = ln_g[ob + ln], bv = ln_b[ob + ln], b3v = b3[ob + ln];
    #pragma unroll
    for (int mf = 0; mf < 4; ++mf)
        #pragma unroll
        for (int r = 0; r < 4; ++r) {
            int t = wt + mf*16 + quad*4 + r;
            float2 p0 = ps[t*4], p1 = ps[t*4 + 1], p2 = ps[t*4 + 2], p3 = ps[t*4 + 3];
            float mean = (p0.x + p1.x + p2.x + p3.x) * 0.015625f;
            float var  = (p0.y + p1.y + p2.y + p3.y) * 0.015625f - mean * mean;
            float inv  = rsqrtf(var + 1e-5f);
            float v = (acc[mf][r] - mean) * inv * gv + bv;
            v = v > 0.f ? v : 0.f;
            xL[t*72 + ob + ln] = (__bf16)v;
        }
    __syncthreads();

    // ---------- P5: out = x @ W3 + b3 (64 tok x 16 cols per wave) ----------
    f32x4 a3[4] = {};
    #pragma unroll
    for (int kb = 0; kb < 2; ++kb) {
        bf16x8 bfr = *(const bf16x8*)(W3bt + ((kb*4 + quad)*64 + ob + ln)*8);
        #pragma unroll
        for (int mf = 0; mf < 4; ++mf) {
            bf16x8 af = *(const bf16x8*)(xL + (wt + mf*16 + ln)*72 + kb*32 + quad*8);
            a3[mf] = MFMA16(af, bfr, a3[mf]);
        }
    }
    #pragma unroll
    for (int mf = 0; mf < 4; ++mf)
        #pragma unroll
        for (int r = 0; r < 4; ++r) {
            long t = tb + wt + mf*16 + quad*4 + r;
            out[t*64 + ob + ln] = a3[mf][r] + b3v;
        }
}

extern "C" void kernel_launch(void* const* d_in, const int* in_sizes, int n_in,
                              void* d_out, int out_size, void* d_ws, size_t ws_size,
                              hipStream_t stream)
{
    const float* img  = (const float*)d_in[0];
    const float* loc  = (const float*)d_in[1];
    const float* W11  = (const float*)d_in[2];
    const float* b11  = (const float*)d_in[3];
    const float* W12  = (const float*)d_in[4];
    const float* b12  = (const float*)d_in[5];
    const float* W21  = (const float*)d_in[6];
    const float* b21  = (const float*)d_in[7];
    const float* W22  = (const float*)d_in[8];
    const float* b22  = (const float*)d_in[9];
    const float* ln_g = (const float*)d_in[10];
    const float* ln_b = (const float*)d_in[11];
    const float* W3   = (const float*)d_in[12];
    const float* b3   = (const float*)d_in[13];
    __bf16* ws = (__bf16*)d_ws;
    float*  o  = (float*)d_out;

    prep_kernel<<<71, 256, 0, stream>>>(W22, b22, W11, W21, W12, W3, ws);
    main_kernel<<<256, 512, 0, stream>>>(img, loc, b11, b12, b21, ln_g, ln_b, b3, ws, o);
}